// Round 2
// baseline (302.640 us; speedup 1.0000x reference)
//
#include <hip/hip_runtime.h>
#include <stdint.h>

typedef float f32x4 __attribute__((ext_vector_type(4)));
typedef __bf16 bf16x8 __attribute__((ext_vector_type(8)));
typedef unsigned short ushortx8 __attribute__((ext_vector_type(8)));

#define D_DIM 512
#define KGC 10
#define NCLU 8
#define BATCH 32
#define WPOS 250
#define WPAD 256
#define KDIM 3584   // 512*7
#define MROWS 522   // 512 feat + 10 assign
#define MPAD 528    // Y rows allocated per batch
#define WROWS 640   // Wcat rows allocated (5 * 128)

__device__ __forceinline__ float bf2f(unsigned short u) {
  union { unsigned int i; float f; } v; v.i = ((unsigned int)u) << 16; return v.f;
}
__device__ __forceinline__ unsigned short f2bf(float f) {
  union { float f; unsigned int i; } v; v.f = f;
  unsigned int r = v.i + 0x7FFFu + ((v.i >> 16) & 1u);
  return (unsigned short)(r >> 16);
}

__device__ __forceinline__ void load_lds16(const void* g, void* l) {
  __builtin_amdgcn_global_load_lds(
      (const __attribute__((address_space(1))) void*)g,
      (__attribute__((address_space(3))) void*)l, 16, 0, 0);
}

// ---------------- prep: Wcat(bf16) = [feat_w ; assign_w ; zeros], bcat fp32 ----------------
__global__ void prep_kernel(const float* __restrict__ fw,
                            const float* __restrict__ fb,
                            const float* __restrict__ aw,
                            const float* __restrict__ ab,
                            unsigned short* __restrict__ Wcat,
                            float* __restrict__ bcat) {
  int r = blockIdx.x;
  unsigned short* dst = Wcat + (size_t)r * KDIM;
  if (r < D_DIM) {
    const float* s = fw + (size_t)r * KDIM;
    for (int k = threadIdx.x; k < KDIM; k += 256) dst[k] = f2bf(s[k]);
  } else if (r < MROWS) {
    const float* s = aw + (size_t)(r - D_DIM) * KDIM;
    for (int k = threadIdx.x; k < KDIM; k += 256) dst[k] = f2bf(s[k]);
  } else {
    for (int k = threadIdx.x; k < KDIM; k += 256) dst[k] = 0;
  }
  if (threadIdx.x == 0)
    bcat[r] = r < D_DIM ? fb[r] : (r < MROWS ? ab[r - D_DIM] : 0.f);
}

// ---------------- transpose: x[b][k][n] (fp32) -> Xt[b][n][k] (bf16), n padded to 256 ----------------
__global__ __launch_bounds__(256) void transpose_kernel(
    const float* __restrict__ x, unsigned short* __restrict__ Xt) {
  __shared__ unsigned short tile[64][66];  // 66: 132B row stride -> conflict-free both phases
  int kt = blockIdx.x * 64, nt = blockIdx.y * 64, b = blockIdx.z;
  const float* xb = x + (size_t)b * (D_DIM * 7 * WPOS);
  int tn = threadIdx.x & 63, t4 = threadIdx.x >> 6;
#pragma unroll
  for (int r = 0; r < 64; r += 4) {
    int k = kt + r + t4;
    int n = nt + tn;
    tile[r + t4][tn] = (n < WPOS) ? f2bf(xb[(size_t)k * WPOS + n]) : (unsigned short)0;
  }
  __syncthreads();
  unsigned short* xtb = Xt + (size_t)b * WPAD * KDIM;
#pragma unroll
  for (int r = 0; r < 64; r += 4) {
    int n = nt + r + t4;
    xtb[(size_t)n * KDIM + kt + tn] = tile[tn][r + t4];
  }
}

// ---------------- GEMM: Y[b][m][n] = relu_if_feat( Wcat[m][:] . Xt[b][n][:] + bcat[m] ) ----------------
#define BM 128
#define BN 128
#define BK 64

__global__ __launch_bounds__(256) void gemm_kernel(
    const unsigned short* __restrict__ Xt, const unsigned short* __restrict__ Wcat,
    const float* __restrict__ bcat, unsigned short* __restrict__ Y) {
  __shared__ __align__(16) unsigned short Wl[BM * BK];  // [m][k]
  __shared__ __align__(16) unsigned short Xl[BN * BK];  // [n][k]
  const int tid = threadIdx.x;
  const int mt = blockIdx.x, nt = blockIdx.y, b = blockIdx.z;
  const int lane = tid & 63, wv = tid >> 6;
  const unsigned short* Wg = Wcat + (size_t)mt * BM * KDIM;
  const unsigned short* Xg = Xt + (size_t)b * WPAD * KDIM + (size_t)nt * BN * KDIM;

  const f32x4 zero = {0.f, 0.f, 0.f, 0.f};
  f32x4 acc[4][4];
#pragma unroll
  for (int i = 0; i < 4; i++)
#pragma unroll
    for (int j = 0; j < 4; j++) acc[i][j] = zero;

  const int wm = (wv & 1) * 64, wn = (wv >> 1) * 64;
  const int fr = lane & 15, kg = lane >> 4;

  for (int kb = 0; kb < KDIM; kb += BK) {
    __syncthreads();
#pragma unroll
    for (int i = 0; i < 4; i++) {
      int s = i * 256 + tid;
      load_lds16(Wg + (size_t)(s >> 3) * KDIM + kb + (s & 7) * 8, &Wl[s * 8]);
    }
#pragma unroll
    for (int i = 0; i < 4; i++) {
      int s = i * 256 + tid;
      load_lds16(Xg + (size_t)(s >> 3) * KDIM + kb + (s & 7) * 8, &Xl[s * 8]);
    }
    __syncthreads();
#pragma unroll
    for (int ks = 0; ks < BK; ks += 32) {
      bf16x8 af[4], bfr[4];
#pragma unroll
      for (int i = 0; i < 4; i++)
        af[i] = *(const bf16x8*)&Wl[(wm + i * 16 + fr) * BK + ks + kg * 8];
#pragma unroll
      for (int j = 0; j < 4; j++)
        bfr[j] = *(const bf16x8*)&Xl[(wn + j * 16 + fr) * BK + ks + kg * 8];
#pragma unroll
      for (int i = 0; i < 4; i++)
#pragma unroll
        for (int j = 0; j < 4; j++)
          acc[i][j] = __builtin_amdgcn_mfma_f32_16x16x32_bf16(af[i], bfr[j], acc[i][j], 0, 0, 0);
    }
  }

  // C/D layout: col = lane&15 (n), row = (lane>>4)*4 + reg (m)
  unsigned short* Yb = Y + (size_t)b * MPAD * WPAD;
  const int m0 = mt * BM + wm + kg * 4;
  const int n0 = nt * BN + wn + fr;
#pragma unroll
  for (int i = 0; i < 4; i++) {
#pragma unroll
    for (int r = 0; r < 4; r++) {
      int m = m0 + i * 16 + r;
      if (m < MPAD) {
        float bias = bcat[m];
#pragma unroll
        for (int j = 0; j < 4; j++) {
          float v = acc[i][j][r] + bias;
          if (m < D_DIM) v = fmaxf(v, 0.f);
          Yb[(size_t)m * WPAD + n0 + j * 16] = f2bf(v);
        }
      }
    }
  }
}

// ---------------- epilogue: softmax, agg, subtract centroids*s_sum, L2-normalize ----------------
__global__ __launch_bounds__(256) void epi_kernel(
    const unsigned short* __restrict__ Y, const float* __restrict__ cent,
    float* __restrict__ out) {
  __shared__ float soft[WPAD];
  __shared__ float red[4];
  const int b = blockIdx.x >> 3, k = blockIdx.x & 7;
  const int tid = threadIdx.x;
  const unsigned short* Yb = Y + (size_t)b * MPAD * WPAD;

  // softmax over the 10 assign logits at position tid; padding cols (>=250) masked to 0
  float sv = 0.f;
  if (tid < WPOS) {
    float lg[KGC];
    float mx = -1e30f;
#pragma unroll
    for (int j = 0; j < KGC; j++) {
      lg[j] = bf2f(Yb[(size_t)(D_DIM + j) * WPAD + tid]);
      mx = fmaxf(mx, lg[j]);
    }
    float s = 0.f, ek = 0.f;
#pragma unroll
    for (int j = 0; j < KGC; j++) {
      float e = __expf(lg[j] - mx);
      s += e;
      if (j == k) ek = e;
    }
    sv = ek / s;
  }
  soft[tid] = sv;
  __syncthreads();

  // s_sum = sum_w soft
  float v = sv;
#pragma unroll
  for (int o = 32; o > 0; o >>= 1) v += __shfl_down(v, o, 64);
  if ((tid & 63) == 0) red[tid >> 6] = v;
  __syncthreads();
  float ssum = red[0] + red[1] + red[2] + red[3];

  // agg over positions for d = tid and d = tid+256
  float a0 = 0.f, a1 = 0.f;
  const unsigned short* row0 = Yb + (size_t)tid * WPAD;
  const unsigned short* row1 = Yb + (size_t)(tid + 256) * WPAD;
  for (int w = 0; w < WPAD; w += 8) {
    ushortx8 f0 = *(const ushortx8*)(row0 + w);
    ushortx8 f1 = *(const ushortx8*)(row1 + w);
#pragma unroll
    for (int u = 0; u < 8; u++) {
      float s = soft[w + u];
      a0 += bf2f(f0[u]) * s;
      a1 += bf2f(f1[u]) * s;
    }
  }
  float c0 = a0 - cent[(size_t)tid * KGC + k] * ssum;
  float c1 = a1 - cent[(size_t)(tid + 256) * KGC + k] * ssum;

  __syncthreads();  // red reuse
  float q = c0 * c0 + c1 * c1;
#pragma unroll
  for (int o = 32; o > 0; o >>= 1) q += __shfl_down(q, o, 64);
  if ((tid & 63) == 0) red[tid >> 6] = q;
  __syncthreads();
  float norm = sqrtf(red[0] + red[1] + red[2] + red[3]);
  float inv = 1.f / fmaxf(norm, 1e-12f);

  float* ob = out + (size_t)b * (NCLU * D_DIM) + (size_t)k * D_DIM;
  ob[tid] = c0 * inv;
  ob[tid + 256] = c1 * inv;
}

extern "C" void kernel_launch(void* const* d_in, const int* in_sizes, int n_in,
                              void* d_out, int out_size, void* d_ws, size_t ws_size,
                              hipStream_t stream) {
  const float* x  = (const float*)d_in[0];
  const float* fw = (const float*)d_in[1];
  const float* fb = (const float*)d_in[2];
  const float* aw = (const float*)d_in[3];
  const float* ab = (const float*)d_in[4];
  const float* ce = (const float*)d_in[5];
  float* out = (float*)d_out;
  char* ws = (char*)d_ws;

  const size_t XT_BYTES = (size_t)BATCH * WPAD * KDIM * 2;  // 58,720,256
  const size_t WC_BYTES = (size_t)WROWS * KDIM * 2;         //  4,587,520
  const size_t BC_BYTES = (size_t)WROWS * 4;                //      2,560
  unsigned short* Xt = (unsigned short*)(ws);
  unsigned short* Wc = (unsigned short*)(ws + XT_BYTES);
  float*          bc = (float*)(ws + XT_BYTES + WC_BYTES);
  unsigned short* Yv = (unsigned short*)(ws + XT_BYTES + WC_BYTES + BC_BYTES);
  // total ws use ~72 MB (Y: 32*528*256*2 = 8,650,752)

  prep_kernel<<<WROWS, 256, 0, stream>>>(fw, fb, aw, ab, Wc, bc);
  transpose_kernel<<<dim3(KDIM / 64, WPAD / 64, BATCH), 256, 0, stream>>>(x, Xt);
  gemm_kernel<<<dim3(5, 2, BATCH), 256, 0, stream>>>(Xt, Wc, bc, Yv);
  epi_kernel<<<BATCH * NCLU, 256, 0, stream>>>(Yv, ce, out);
}

// Round 3
// 261.702 us; speedup vs baseline: 1.1564x; 1.1564x over previous
//
#include <hip/hip_runtime.h>
#include <stdint.h>

typedef float f32x4 __attribute__((ext_vector_type(4)));
typedef __bf16 bf16x8 __attribute__((ext_vector_type(8)));
typedef unsigned short ushortx8 __attribute__((ext_vector_type(8)));

#define D_DIM 512
#define KGC 10
#define NCLU 8
#define BATCH 32
#define WPOS 250
#define WPAD 256
#define KDIM 3584   // 512*7
#define MROWS 522   // 512 feat + 10 assign
#define MPAD 528    // Y rows allocated per batch
#define WROWS 640   // Wcat rows allocated (5 * 128)

__device__ __forceinline__ float bf2f(unsigned short u) {
  union { unsigned int i; float f; } v; v.i = ((unsigned int)u) << 16; return v.f;
}
__device__ __forceinline__ unsigned short f2bf(float f) {
  union { float f; unsigned int i; } v; v.f = f;
  unsigned int r = v.i + 0x7FFFu + ((v.i >> 16) & 1u);
  return (unsigned short)(r >> 16);
}

__device__ __forceinline__ void load_lds16(const void* g, void* l) {
  __builtin_amdgcn_global_load_lds(
      (const __attribute__((address_space(1))) void*)g,
      (__attribute__((address_space(3))) void*)l, 16, 0, 0);
}

// ---------------- prep: Wcat(bf16) = [feat_w ; assign_w ; zeros], bcat fp32 ----------------
__global__ void prep_kernel(const float* __restrict__ fw,
                            const float* __restrict__ fb,
                            const float* __restrict__ aw,
                            const float* __restrict__ ab,
                            unsigned short* __restrict__ Wcat,
                            float* __restrict__ bcat) {
  int r = blockIdx.x;
  unsigned short* dst = Wcat + (size_t)r * KDIM;
  const float* src = (r < D_DIM) ? (fw + (size_t)r * KDIM)
                   : (r < MROWS) ? (aw + (size_t)(r - D_DIM) * KDIM)
                                 : nullptr;
  for (int i = threadIdx.x; i < KDIM / 4; i += 256) {  // 896 float4 per row
    unsigned short o0 = 0, o1 = 0, o2 = 0, o3 = 0;
    if (src) {
      float4 v = ((const float4*)src)[i];
      o0 = f2bf(v.x); o1 = f2bf(v.y); o2 = f2bf(v.z); o3 = f2bf(v.w);
    }
    ushortx8 dummy;  // avoid; use ushort4 via struct
    ushort4 o; o.x = o0; o.y = o1; o.z = o2; o.w = o3;
    ((ushort4*)dst)[i] = o;
  }
  if (threadIdx.x == 0)
    bcat[r] = r < D_DIM ? fb[r] : (r < MROWS ? ab[r - D_DIM] : 0.f);
}

// ---------------- transpose: x[b][k][n] (fp32) -> Xt[row=b*256+n][k] (bf16) ----------------
__global__ __launch_bounds__(256) void transpose_kernel(
    const float* __restrict__ x, unsigned short* __restrict__ Xt) {
  __shared__ unsigned short tile[64][66];  // 132B stride: conflict-free/low-conflict both phases
  const int kt = blockIdx.x * 64, nt = blockIdx.y * 64, b = blockIdx.z;
  const float* xb = x + (size_t)b * (KDIM * WPOS);
  const int t = threadIdx.x;
  // phase 1: 64 k-rows x 32 float2 along n
#pragma unroll
  for (int it = 0; it < 8; it++) {
    int id = it * 256 + t;
    int k = id >> 5, p = id & 31;
    int n = nt + p * 2;
    float vx = 0.f, vy = 0.f;
    if (n < WPOS) {  // n even, WPOS even -> pair fully in-bounds
      float2 v = *(const float2*)&xb[(size_t)(kt + k) * WPOS + n];
      vx = v.x; vy = v.y;
    }
    ushort2 o; o.x = f2bf(vx); o.y = f2bf(vy);
    *(ushort2*)&tile[k][p * 2] = o;
  }
  __syncthreads();
  // phase 2: 64 n-rows x 32 ushort2 along k
  unsigned short* xtb = Xt + (size_t)(b * WPAD + nt) * KDIM;
#pragma unroll
  for (int it = 0; it < 8; it++) {
    int id = it * 256 + t;
    int n = id >> 5, q = id & 31;
    ushort2 o; o.x = tile[2 * q][n]; o.y = tile[2 * q + 1][n];
    *(ushort2*)&xtb[(size_t)n * KDIM + kt + 2 * q] = o;
  }
}

// ---------------- GEMM: Y[b][m][n] = relu_if_feat( Wcat[m][:] . Xt[n_glob][:] + bcat[m] ) ----------------
// 128m x 64n x 64k tiles, grid (5, 128) = 640 blocks. XOR-swizzled 16B k-blocks in LDS.
#define BM 128
#define BN 64
#define BK 64

__global__ __launch_bounds__(256) void gemm_kernel(
    const unsigned short* __restrict__ Xt, const unsigned short* __restrict__ Wcat,
    const float* __restrict__ bcat, unsigned short* __restrict__ Y) {
  __shared__ __align__(16) unsigned short Wl[BM * BK];  // [m][k-blocks swizzled]
  __shared__ __align__(16) unsigned short Xl[BN * BK];  // [n][k-blocks swizzled]
  const int tid = threadIdx.x;
  const int mt = blockIdx.x, ntg = blockIdx.y;
  const int lane = tid & 63, wv = tid >> 6;
  const unsigned short* Wg = Wcat + (size_t)mt * BM * KDIM;
  const unsigned short* Xg = Xt + (size_t)ntg * BN * KDIM;

  const f32x4 zero = {0.f, 0.f, 0.f, 0.f};
  f32x4 acc[2][4];
#pragma unroll
  for (int i = 0; i < 2; i++)
#pragma unroll
    for (int j = 0; j < 4; j++) acc[i][j] = zero;

  const int wm = wv * 32;            // wave covers 32 m-rows x all 64 n
  const int fr = lane & 15, kg = lane >> 4;
  const int sx = fr & 7;             // frag-read swizzle

  for (int kb = 0; kb < KDIM; kb += BK) {
    __syncthreads();
    // stage W: 128 rows x 8 16B-blocks; dest slot (row,p) <- src k-block (p ^ (row&7))
#pragma unroll
    for (int i = 0; i < 4; i++) {
      int s = i * 256 + tid;
      int row = s >> 3, p = s & 7;
      int blk = p ^ (row & 7);
      load_lds16(Wg + (size_t)row * KDIM + kb + blk * 8, &Wl[s * 8]);
    }
    // stage X: 64 rows x 8 blocks
#pragma unroll
    for (int i = 0; i < 2; i++) {
      int s = i * 256 + tid;
      int row = s >> 3, p = s & 7;
      int blk = p ^ (row & 7);
      load_lds16(Xg + (size_t)row * KDIM + kb + blk * 8, &Xl[s * 8]);
    }
    __syncthreads();
#pragma unroll
    for (int ks = 0; ks < BK; ks += 32) {
      const int kb8 = (ks >> 3) + kg;  // source k-block wanted by this lane
      bf16x8 af[2], bfr[4];
#pragma unroll
      for (int i = 0; i < 2; i++)
        af[i] = *(const bf16x8*)&Wl[(wm + i * 16 + fr) * BK + (kb8 ^ sx) * 8];
#pragma unroll
      for (int j = 0; j < 4; j++)
        bfr[j] = *(const bf16x8*)&Xl[(j * 16 + fr) * BK + (kb8 ^ sx) * 8];
#pragma unroll
      for (int i = 0; i < 2; i++)
#pragma unroll
        for (int j = 0; j < 4; j++)
          acc[i][j] = __builtin_amdgcn_mfma_f32_16x16x32_bf16(af[i], bfr[j], acc[i][j], 0, 0, 0);
    }
  }

  // C/D layout: col = lane&15 (n), row = (lane>>4)*4 + reg (m)
  const int b = ntg >> 2;                  // 4 n-tiles per batch
  const int nb = (ntg & 3) * BN;
  unsigned short* Yb = Y + (size_t)b * MPAD * WPAD;
  const int m0 = mt * BM + wm + kg * 4;
  const int n0 = nb + fr;
#pragma unroll
  for (int i = 0; i < 2; i++) {
#pragma unroll
    for (int r = 0; r < 4; r++) {
      int m = m0 + i * 16 + r;
      if (m < MPAD) {
        float bias = bcat[m];
#pragma unroll
        for (int j = 0; j < 4; j++) {
          float v = acc[i][j][r] + bias;
          if (m < D_DIM) v = fmaxf(v, 0.f);
          Yb[(size_t)m * WPAD + n0 + j * 16] = f2bf(v);
        }
      }
    }
  }
}

// ---------------- epilogue: softmax, agg, subtract centroids*s_sum, L2-normalize ----------------
__global__ __launch_bounds__(256) void epi_kernel(
    const unsigned short* __restrict__ Y, const float* __restrict__ cent,
    float* __restrict__ out) {
  __shared__ float soft[WPAD];
  __shared__ float red[4];
  const int b = blockIdx.x >> 3, k = blockIdx.x & 7;
  const int tid = threadIdx.x;
  const unsigned short* Yb = Y + (size_t)b * MPAD * WPAD;

  // softmax over the 10 assign logits at position tid; padding cols (>=250) masked to 0
  float sv = 0.f;
  if (tid < WPOS) {
    float lg[KGC];
    float mx = -1e30f;
#pragma unroll
    for (int j = 0; j < KGC; j++) {
      lg[j] = bf2f(Yb[(size_t)(D_DIM + j) * WPAD + tid]);
      mx = fmaxf(mx, lg[j]);
    }
    float s = 0.f, ek = 0.f;
#pragma unroll
    for (int j = 0; j < KGC; j++) {
      float e = __expf(lg[j] - mx);
      s += e;
      if (j == k) ek = e;
    }
    sv = ek / s;
  }
  soft[tid] = sv;
  __syncthreads();

  // s_sum = sum_w soft
  float v = sv;
#pragma unroll
  for (int o = 32; o > 0; o >>= 1) v += __shfl_down(v, o, 64);
  if ((tid & 63) == 0) red[tid >> 6] = v;
  __syncthreads();
  float ssum = red[0] + red[1] + red[2] + red[3];

  // agg over positions for d = tid and d = tid+256
  float a0 = 0.f, a1 = 0.f;
  const unsigned short* row0 = Yb + (size_t)tid * WPAD;
  const unsigned short* row1 = Yb + (size_t)(tid + 256) * WPAD;
  for (int w = 0; w < WPAD; w += 8) {
    ushortx8 f0 = *(const ushortx8*)(row0 + w);
    ushortx8 f1 = *(const ushortx8*)(row1 + w);
#pragma unroll
    for (int u = 0; u < 8; u++) {
      float s = soft[w + u];
      a0 += bf2f(f0[u]) * s;
      a1 += bf2f(f1[u]) * s;
    }
  }
  float c0 = a0 - cent[(size_t)tid * KGC + k] * ssum;
  float c1 = a1 - cent[(size_t)(tid + 256) * KGC + k] * ssum;

  __syncthreads();  // red reuse
  float q = c0 * c0 + c1 * c1;
#pragma unroll
  for (int o = 32; o > 0; o >>= 1) q += __shfl_down(q, o, 64);
  if ((tid & 63) == 0) red[tid >> 6] = q;
  __syncthreads();
  float norm = sqrtf(red[0] + red[1] + red[2] + red[3]);
  float inv = 1.f / fmaxf(norm, 1e-12f);

  float* ob = out + (size_t)b * (NCLU * D_DIM) + (size_t)k * D_DIM;
  ob[tid] = c0 * inv;
  ob[tid + 256] = c1 * inv;
}

extern "C" void kernel_launch(void* const* d_in, const int* in_sizes, int n_in,
                              void* d_out, int out_size, void* d_ws, size_t ws_size,
                              hipStream_t stream) {
  const float* x  = (const float*)d_in[0];
  const float* fw = (const float*)d_in[1];
  const float* fb = (const float*)d_in[2];
  const float* aw = (const float*)d_in[3];
  const float* ab = (const float*)d_in[4];
  const float* ce = (const float*)d_in[5];
  float* out = (float*)d_out;
  char* ws = (char*)d_ws;

  const size_t XT_BYTES = (size_t)BATCH * WPAD * KDIM * 2;  // 58,720,256
  const size_t WC_BYTES = (size_t)WROWS * KDIM * 2;         //  4,587,520
  const size_t BC_BYTES = (size_t)WROWS * 4;                //      2,560
  unsigned short* Xt = (unsigned short*)(ws);
  unsigned short* Wc = (unsigned short*)(ws + XT_BYTES);
  float*          bc = (float*)(ws + XT_BYTES + WC_BYTES);
  unsigned short* Yv = (unsigned short*)(ws + XT_BYTES + WC_BYTES + BC_BYTES);
  // total ws use ~72 MB (Y: 32*528*256*2 = 8,650,752)

  prep_kernel<<<WROWS, 256, 0, stream>>>(fw, fb, aw, ab, Wc, bc);
  transpose_kernel<<<dim3(KDIM / 64, WPAD / 64, BATCH), 256, 0, stream>>>(x, Xt);
  gemm_kernel<<<dim3(5, 128), 256, 0, stream>>>(Xt, Wc, bc, Yv);
  epi_kernel<<<BATCH * NCLU, 256, 0, stream>>>(Yv, ce, out);
}